// Round 3
// baseline (679.953 us; speedup 1.0000x reference)
//
#include <hip/hip_runtime.h>
#include <hip/hip_bf16.h>

typedef unsigned short u16;
typedef unsigned int u32;
typedef unsigned long long u64;
typedef __attribute__((ext_vector_type(8))) short short8;
typedef __attribute__((ext_vector_type(4))) float f32x4;

#define DI __device__ __forceinline__

DI float b2f(u16 v){ u32 u = ((u32)v) << 16; float f; __builtin_memcpy(&f, &u, 4); return f; }
DI u16 f2bu(float f){ __hip_bfloat16 h = __float2bfloat16(f); u16 u; __builtin_memcpy(&u, &h, 2); return u; }

// ---------- kprep: xT[n][x=(t,v)][ci] = bf16(x[n][ci][x])  (fp32 -> bf16 transpose) ----------
__global__ __launch_bounds__(256) void kprep(const float* __restrict__ x, u16* __restrict__ xT){
  __shared__ u16 tile[128*72];
  const int xb = blockIdx.x, n = blockIdx.y, tid = threadIdx.x;
  const int x0 = xb*128;
  const int ci = tid>>2, part = tid&3;
  const float* src = x + ((size_t)(n*64+ci))*6400 + x0 + part*32;
  #pragma unroll
  for (int i=0;i<8;i++){
    float4 f = ((const float4*)src)[i];
    const int col = part*32 + i*4;
    tile[(col+0)*72+ci] = f2bu(f.x);
    tile[(col+1)*72+ci] = f2bu(f.y);
    tile[(col+2)*72+ci] = f2bu(f.z);
    tile[(col+3)*72+ci] = f2bu(f.w);
  }
  __syncthreads();
  const int row = tid>>1, half = tid&1;
  short8* dst = (short8*)(xT + ((size_t)n*6400 + x0 + row)*64 + half*32);
  const short8* s8 = (const short8*)(tile + row*72 + half*32);
  #pragma unroll
  for (int i=0;i<4;i++) dst[i] = s8[i];
}

// ---------- kzero: xm = 0 ----------
__global__ __launch_bounds__(256) void kzero(float* __restrict__ xm){
  const int i = blockIdx.x*1024 + threadIdx.x*4;   // 50 blocks -> 51200 floats
  float4 z = {0.f,0.f,0.f,0.f};
  *(float4*)(xm + i) = z;
}

// ---------- kmean: xm[n][c][v] += partial mean_t xT ----------
__global__ __launch_bounds__(256) void kmean(const u16* __restrict__ xT, float* __restrict__ xm){
  __shared__ float part[4][1600];
  const int seg = blockIdx.x, n = blockIdx.y, tid = threadIdx.x;
  const int tg = tid>>6, c = tid&63;
  float acc[25];
  #pragma unroll
  for (int v=0;v<25;v++) acc[v]=0.f;
  for (int t = seg*32 + tg; t < seg*32 + 32; t += 4){
    const u16* base = xT + ((size_t)n*6400 + t*25)*64 + c;
    #pragma unroll
    for (int v=0;v<25;v++) acc[v] += b2f(base[v*64]);
  }
  #pragma unroll
  for (int v=0;v<25;v++) part[tg][v*64+c] = acc[v];
  __syncthreads();
  for (int idx = tid; idx < 1600; idx += 256){
    const int v = idx>>6, cc = idx&63;
    const float m = part[0][idx]+part[1][idx]+part[2][idx]+part[3][idx];
    atomicAdd(&xm[(n*64+cc)*25+v], m*(1.f/256.f));
  }
}

// ---------- kp: p[n][c][v] = softmax_v(-(w2@xm+b2));  rsA[u]=sum_v A[u,v] ----------
__global__ __launch_bounds__(64) void kp(const float* __restrict__ xm, const float* __restrict__ w2,
                                         const float* __restrict__ b2p, const float* __restrict__ Ab,
                                         float* __restrict__ p, float* __restrict__ rsA){
  const int c = blockIdx.x, n = blockIdx.y, lane = threadIdx.x;
  __shared__ float sc[32];
  __shared__ float red[2];
  float neg = 0.f;
  if (lane < 25){
    float acc = b2p[c];
    for (int k = 0; k < 64; k++) acc += w2[c*64 + k] * xm[(n*64 + k)*25 + lane];
    neg = -acc;
    sc[lane] = neg;
  }
  __syncthreads();
  if (lane == 0){
    float m = sc[0];
    for (int i = 1; i < 25; i++) m = fmaxf(m, sc[i]);
    red[0] = m;
  }
  __syncthreads();
  float e = 0.f;
  if (lane < 25){ e = expf(neg - red[0]); sc[lane] = e; }
  __syncthreads();
  if (lane == 0){
    float ssum = 0.f;
    for (int i = 0; i < 25; i++) ssum += sc[i];
    red[1] = ssum;
  }
  __syncthreads();
  if (lane < 25) p[(n*32 + c)*25 + lane] = e / red[1];
  if (n == 0 && c == 0 && lane < 25){
    float r = 0.f;
    for (int v = 0; v < 25; v++) r += Ab[lane*25 + v];
    rsA[lane] = r;
  }
}

// ---------- kxa: xA[n][x=(t,u)][k] = bf16( sum_v A[u,v] * xT[n][(t,v)][k] ) ----------
__global__ __launch_bounds__(256) void kxa(const u16* __restrict__ xT, const float* __restrict__ Ab,
                                           u16* __restrict__ xA){
  __shared__ float xl[200*68];
  __shared__ float al[625];
  const int tc = blockIdx.x, n = blockIdx.y, tid = threadIdx.x;
  const int x0t = tc * 200;
  for (int i = tid; i < 625; i += 256) al[i] = Ab[i];
  for (int idx = tid; idx < 1600; idx += 256){
    const int r = idx>>3, i = idx&7;
    short8 v = *(const short8*)(xT + ((size_t)n*6400 + x0t + r)*64 + i*8);
    float* dst = xl + r*68 + i*8;
    #pragma unroll
    for (int e=0;e<8;e++) dst[e] = b2f((u16)v[e]);
  }
  __syncthreads();
  if (tid < 200){
    const int t_ = tid / 25, u = tid % 25;
    float acc[64];
    #pragma unroll
    for (int k = 0; k < 64; k++) acc[k] = 0.f;
    const float* arow = al + u*25;
    for (int v = 0; v < 25; v++){
      const float a = arow[v];
      const float* xr = xl + (t_*25 + v)*68;
      #pragma unroll
      for (int k = 0; k < 64; k++) acc[k] += a * xr[k];
    }
    u16* dst = xA + ((size_t)n*6400 + x0t + tid)*64;
    #pragma unroll
    for (int k = 0; k < 64; k += 4){
      u64 pk = (u64)f2bu(acc[k]) | ((u64)f2bu(acc[k+1])<<16)
             | ((u64)f2bu(acc[k+2])<<32) | ((u64)f2bu(acc[k+3])<<48);
      *(u64*)(dst + k) = pk;
    }
  }
}

// ---------- kwt: wtb[dt][co][ci] = bf16(wt[co][ci][dt]) ----------
__global__ __launch_bounds__(256) void kwt(const float* __restrict__ wt, u16* __restrict__ wtb){
  const int o = blockIdx.x*256 + threadIdx.x;   // < 147456
  const int dt = o >> 14, rem = o & 16383;
  wtb[o] = f2bu(wt[rem*9 + dt]);
}

// ---------- kwr: wrb[co][ci] = bf16( wr[co][ci] * R0[co] / E0[co] ) ----------
__global__ __launch_bounds__(256) void kwr(const float* __restrict__ wrw, const float* __restrict__ g2,
                                           const float* __restrict__ v2, const float* __restrict__ gr,
                                           const float* __restrict__ vr, u16* __restrict__ wrb){
  const int o = blockIdx.x*256 + threadIdx.x;   // < 8192
  const int co = o >> 6;
  const float E0 = g2[co]*rsqrtf(v2[co]+1e-5f);
  const float R0 = gr[co]*rsqrtf(vr[co]+1e-5f);
  wrb[o] = f2bu(wrw[o]*R0/E0);
}

// ---------- khpad: zero t-pad rows of h ----------
__global__ __launch_bounds__(256) void khpad(u16* __restrict__ h){
  const int n = blockIdx.x, side = blockIdx.y, tid = threadIdx.x;
  short8* base = (short8*)(h + ((size_t)n*6600 + (side ? 6500 : 0))*128);
  short8 z = {0,0,0,0,0,0,0,0};
  for (int i = tid; i < 1600; i += 256) base[i] = z;
}

// ---------- ks: s[n][co][t] = sum_v p[n][co&31][v] * (w3@x)[n][co][(t,v)] ----------
__global__ __launch_bounds__(256) void ks(const u16* __restrict__ xT, const float* __restrict__ w3,
                                          const float* __restrict__ p, float* __restrict__ s){
  __shared__ __align__(16) u16 aL[128*72];
  __shared__ __align__(16) u16 bL[128*72];
  __shared__ float pL[800];
  __shared__ float sL[512];
  const int xb = blockIdx.x, n = blockIdx.y, tid = threadIdx.x;
  const int x0 = xb*100, t0 = xb*4;
  const int row = tid >> 1, half = tid & 1;
  { // A: bf16(w3[128][64])
    const float* src = w3 + row*64 + half*32;
    u16* dst = aL + row*72 + half*32;
    #pragma unroll
    for (int i=0;i<8;i++){
      float4 f = ((const float4*)src)[i];
      dst[i*4+0]=f2bu(f.x); dst[i*4+1]=f2bu(f.y); dst[i*4+2]=f2bu(f.z); dst[i*4+3]=f2bu(f.w);
    }
  }
  { // B: xT rows x0..x0+99, rows 100..127 zero
    short8* dst = (short8*)(bL + row*72 + half*32);
    if (row < 100){
      const short8* src = (const short8*)(xT + ((size_t)n*6400 + x0 + row)*64 + half*32);
      #pragma unroll
      for (int i=0;i<4;i++) dst[i] = src[i];
    } else {
      short8 z = {0,0,0,0,0,0,0,0};
      #pragma unroll
      for (int i=0;i<4;i++) dst[i] = z;
    }
  }
  for (int i = tid; i < 800; i += 256) pL[i] = p[n*800 + i];
  sL[tid] = 0.f; sL[tid + 256] = 0.f;
  __syncthreads();
  const int wave = tid>>6, lane = tid&63, q = lane>>4, l = lane&15;
  const int wr = wave>>1, wc = wave&1;
  f32x4 acc[4][4];
  #pragma unroll
  for (int i=0;i<4;i++)
    #pragma unroll
    for (int j=0;j<4;j++){ f32x4 z0 = {0.f,0.f,0.f,0.f}; acc[i][j] = z0; }
  #pragma unroll
  for (int ksi = 0; ksi < 2; ksi++){
    const int kb = ksi*32 + q*8;
    short8 af[4], bf[4];
    #pragma unroll
    for (int i=0;i<4;i++) af[i] = *(const short8*)(aL + (wr*64 + i*16 + l)*72 + kb);
    #pragma unroll
    for (int j=0;j<4;j++) bf[j] = *(const short8*)(bL + (wc*64 + j*16 + l)*72 + kb);
    #pragma unroll
    for (int i=0;i<4;i++)
      #pragma unroll
      for (int j=0;j<4;j++)
        acc[i][j] = __builtin_amdgcn_mfma_f32_16x16x32_bf16(af[i], bf[j], acc[i][j], 0, 0, 0);
  }
  #pragma unroll
  for (int i=0;i<4;i++){
    const int co0 = wr*64 + i*16 + q*4;
    #pragma unroll
    for (int j=0;j<4;j++){
      const int colx = wc*64 + j*16 + l;
      if (colx < 100){
        const int u = colx % 25, tt = colx / 25;
        #pragma unroll
        for (int r=0;r<4;r++){
          const float wv = acc[i][j][r] * pL[((co0 + r)&31)*25 + u];
          atomicAdd(&sL[(co0 + r)*4 + tt], wv);
        }
      }
    }
  }
  __syncthreads();
  for (int idx = tid; idx < 512; idx += 256){
    const int co = idx >> 2, tt = idx & 3;
    s[((size_t)n*128 + co)*256 + t0 + tt] = sL[idx];
  }
}

// ---------- ky: h[n][x+100][co] = bf16(relu(bn1(w4@xA + b4*rsA[u] + s + b3))) ----------
__global__ __launch_bounds__(256) void ky(const u16* __restrict__ xA, const float* __restrict__ w4,
      const float* __restrict__ s, const float* __restrict__ b3, const float* __restrict__ b4,
      const float* __restrict__ g1, const float* __restrict__ bb1, const float* __restrict__ m1,
      const float* __restrict__ v1, const float* __restrict__ rsA, u16* __restrict__ h){
  __shared__ __align__(16) u16 aL[128*72];
  __shared__ __align__(16) u16 bL[128*72];
  __shared__ float A0[128], A1[128], A2[128];
  __shared__ float sF[1024];
  __shared__ float rs[32];
  const int xb = blockIdx.x, n = blockIdx.y, tid = threadIdx.x;
  const int x0 = xb*128, tlo = x0/25;
  const int row = tid >> 1, half = tid & 1;
  { // A: bf16(w4)
    const float* src = w4 + row*64 + half*32;
    u16* dst = aL + row*72 + half*32;
    #pragma unroll
    for (int i=0;i<8;i++){
      float4 f = ((const float4*)src)[i];
      dst[i*4+0]=f2bu(f.x); dst[i*4+1]=f2bu(f.y); dst[i*4+2]=f2bu(f.z); dst[i*4+3]=f2bu(f.w);
    }
  }
  { // B: xA rows
    const short8* src = (const short8*)(xA + ((size_t)n*6400 + x0 + row)*64 + half*32);
    short8* dst = (short8*)(bL + row*72 + half*32);
    #pragma unroll
    for (int i=0;i<4;i++) dst[i] = src[i];
  }
  if (tid < 128){
    const float scv = g1[tid] * rsqrtf(v1[tid] + 1e-5f);
    A0[tid] = scv;
    A1[tid] = scv * b4[tid];
    A2[tid] = bb1[tid] - m1[tid] * scv;
  }
  if (tid < 32) rs[tid] = (tid < 25) ? rsA[tid] : 0.f;
  __syncthreads();
  for (int idx = tid; idx < 1024; idx += 256){
    const int co = idx >> 3, tt = idx & 7;
    const int t = tlo + tt;
    const float sv = (t < 256) ? s[((size_t)n*128 + co)*256 + t] : 0.f;
    sF[idx] = A0[co] * (sv + b3[co]) + A2[co];
  }
  const int wave = tid>>6, lane = tid&63, q = lane>>4, l = lane&15;
  const int wr = wave>>1, wc = wave&1;
  f32x4 acc[4][4];
  #pragma unroll
  for (int i=0;i<4;i++)
    #pragma unroll
    for (int j=0;j<4;j++){ f32x4 z0 = {0.f,0.f,0.f,0.f}; acc[i][j] = z0; }
  #pragma unroll
  for (int ksi = 0; ksi < 2; ksi++){
    const int kb = ksi*32 + q*8;
    short8 af[4], bf[4];
    #pragma unroll
    for (int i=0;i<4;i++) af[i] = *(const short8*)(aL + (wr*64 + i*16 + l)*72 + kb);
    #pragma unroll
    for (int j=0;j<4;j++) bf[j] = *(const short8*)(bL + (wc*64 + j*16 + l)*72 + kb);
    #pragma unroll
    for (int i=0;i<4;i++)
      #pragma unroll
      for (int j=0;j<4;j++)
        acc[i][j] = __builtin_amdgcn_mfma_f32_16x16x32_bf16(af[i], bf[j], acc[i][j], 0, 0, 0);
  }
  __syncthreads();
  #pragma unroll
  for (int i=0;i<4;i++){
    const int co0 = wr*64 + i*16 + q*4;
    #pragma unroll
    for (int j=0;j<4;j++){
      const int colx = wc*64 + j*16 + l;
      const int xg = x0 + colx;
      const int u = xg % 25, tt = xg/25 - tlo;
      const float rsu = rs[u];
      u64 pk = 0;
      #pragma unroll
      for (int r=0;r<4;r++){
        const int co = co0 + r;
        float y = A0[co]*acc[i][j][r] + A1[co]*rsu + sF[co*8 + tt];
        y = fmaxf(y, 0.f);
        pk |= ((u64)f2bu(y)) << (16*r);
      }
      *(u64*)(h + ((size_t)n*6600 + xg + 100)*128 + co0) = pk;
    }
  }
}

// ---------- ktcn: out = relu(E0*(conv9(h) + (R0/E0)*wr@x) + E1'), fp32 out [n][co][x] ----------
__global__ __launch_bounds__(256) void ktcn(const u16* __restrict__ h, const u16* __restrict__ wtb,
      const u16* __restrict__ wrb, const u16* __restrict__ xT,
      const float* __restrict__ bt, const float* __restrict__ g2, const float* __restrict__ bb2,
      const float* __restrict__ m2, const float* __restrict__ v2,
      const float* __restrict__ gr, const float* __restrict__ bbr, const float* __restrict__ mr,
      const float* __restrict__ vr, const float* __restrict__ brb,
      float* __restrict__ out){
  __shared__ __align__(16) char smem[69632];
  u16* aL = (u16*)smem;            // 128*136
  u16* bL = (u16*)(smem + 34816);  // 128*136
  float* tr = (float*)smem;        // 128*132 fp32 (reused after GEMM)
  __shared__ float E0s[128], E1s[128];
  const int xb = blockIdx.x, n = blockIdx.y, tid = threadIdx.x;
  const int x0 = xb*128;
  const int wave = tid>>6, lane = tid&63, q = lane>>4, l = lane&15;
  const int wr2 = wave>>1, wc = wave&1;
  const int row = tid >> 1, half = tid & 1;
  if (tid < 128){
    const float scv2 = g2[tid]*rsqrtf(v2[tid]+1e-5f);
    const float scvr = gr[tid]*rsqrtf(vr[tid]+1e-5f);
    E0s[tid] = scv2;
    E1s[tid] = scv2*bt[tid] + bb2[tid] - m2[tid]*scv2
             + (bbr[tid] - mr[tid]*scvr + scvr*brb[tid]);
  }
  f32x4 acc[4][4];
  #pragma unroll
  for (int i=0;i<4;i++)
    #pragma unroll
    for (int j=0;j<4;j++){ f32x4 z0 = {0.f,0.f,0.f,0.f}; acc[i][j] = z0; }
  #pragma unroll 1
  for (int dt = 0; dt < 9; dt++){
    __syncthreads();
    {
      const short8* src = (const short8*)(wtb + dt*16384 + row*128 + half*64);
      short8* dst = (short8*)(aL + row*136 + half*64);
      #pragma unroll
      for (int i = 0; i < 8; i++) dst[i] = src[i];
    }
    {
      const short8* src = (const short8*)(h + ((size_t)n*6600 + x0 + dt*25 + row)*128 + half*64);
      short8* dst = (short8*)(bL + row*136 + half*64);
      #pragma unroll
      for (int i = 0; i < 8; i++) dst[i] = src[i];
    }
    __syncthreads();
    #pragma unroll
    for (int ksi = 0; ksi < 4; ksi++){
      const int kb = ksi*32 + q*8;
      short8 af[4], bf[4];
      #pragma unroll
      for (int i=0;i<4;i++) af[i] = *(const short8*)(aL + (wr2*64 + i*16 + l)*136 + kb);
      #pragma unroll
      for (int j=0;j<4;j++) bf[j] = *(const short8*)(bL + (wc*64 + j*16 + l)*136 + kb);
      #pragma unroll
      for (int i=0;i<4;i++)
        #pragma unroll
        for (int j=0;j<4;j++)
          acc[i][j] = __builtin_amdgcn_mfma_f32_16x16x32_bf16(af[i], bf[j], acc[i][j], 0, 0, 0);
    }
  }
  // residual tap: A = wrb (pre-scaled), B = xT rows, K = 64
  __syncthreads();
  {
    const short8* srcA = (const short8*)(wrb + row*64 + half*32);
    short8* dstA = (short8*)(aL + row*136 + half*32);
    #pragma unroll
    for (int i = 0; i < 4; i++) dstA[i] = srcA[i];
    const short8* srcB = (const short8*)(xT + ((size_t)n*6400 + x0 + row)*64 + half*32);
    short8* dstB = (short8*)(bL + row*136 + half*32);
    #pragma unroll
    for (int i = 0; i < 4; i++) dstB[i] = srcB[i];
  }
  __syncthreads();
  #pragma unroll
  for (int ksi = 0; ksi < 2; ksi++){
    const int kb = ksi*32 + q*8;
    short8 af[4], bf[4];
    #pragma unroll
    for (int i=0;i<4;i++) af[i] = *(const short8*)(aL + (wr2*64 + i*16 + l)*136 + kb);
    #pragma unroll
    for (int j=0;j<4;j++) bf[j] = *(const short8*)(bL + (wc*64 + j*16 + l)*136 + kb);
    #pragma unroll
    for (int i=0;i<4;i++)
      #pragma unroll
      for (int j=0;j<4;j++)
        acc[i][j] = __builtin_amdgcn_mfma_f32_16x16x32_bf16(af[i], bf[j], acc[i][j], 0, 0, 0);
  }
  __syncthreads();
  #pragma unroll
  for (int i=0;i<4;i++){
    const int co0 = wr2*64 + i*16 + q*4;
    #pragma unroll
    for (int j=0;j<4;j++){
      const int colx = wc*64 + j*16 + l;
      #pragma unroll
      for (int r=0;r<4;r++){
        const float yv = E0s[co0+r]*acc[i][j][r] + E1s[co0+r];
        tr[(co0+r)*132 + colx] = fmaxf(yv, 0.f);
      }
    }
  }
  __syncthreads();
  {
    const float4* s4 = (const float4*)(tr + row*132 + half*64);
    float4* d4 = (float4*)(out + ((size_t)n*128 + row)*6400 + x0 + half*64);
    #pragma unroll
    for (int i = 0; i < 16; i++) d4[i] = s4[i];
  }
}

extern "C" void kernel_launch(void* const* d_in, const int* in_sizes, int n_in,
                              void* d_out, int out_size, void* d_ws, size_t ws_size,
                              hipStream_t stream){
  const float* x   = (const float*)d_in[0];
  const float* Ab  = (const float*)d_in[1];
  // d_in[2],d_in[3] = w1,b1: dead (softmax cancellation)
  const float* w2  = (const float*)d_in[4];
  const float* b2p = (const float*)d_in[5];
  const float* w3  = (const float*)d_in[6];
  const float* b3  = (const float*)d_in[7];
  const float* w4  = (const float*)d_in[8];
  const float* b4  = (const float*)d_in[9];
  const float* g1  = (const float*)d_in[10];
  const float* bb1 = (const float*)d_in[11];
  const float* m1  = (const float*)d_in[12];
  const float* v1  = (const float*)d_in[13];
  const float* wt  = (const float*)d_in[14];
  const float* bt  = (const float*)d_in[15];
  const float* g2  = (const float*)d_in[16];
  const float* bb2 = (const float*)d_in[17];
  const float* m2  = (const float*)d_in[18];
  const float* v2  = (const float*)d_in[19];
  const float* wrw = (const float*)d_in[20];
  const float* brb = (const float*)d_in[21];
  const float* gr  = (const float*)d_in[22];
  const float* bbr = (const float*)d_in[23];
  const float* mr  = (const float*)d_in[24];
  const float* vr  = (const float*)d_in[25];
  float* out = (float*)d_out;

  char* ws = (char*)d_ws;
  float* xm  = (float*)(ws);               // 204,800 B
  float* p   = (float*)(ws + 204800);      // 102,400 B
  float* rsA = (float*)(ws + 307200);      // 512 B
  float* s   = (float*)(ws + 307712);      // 4,194,304 B
  u16* xT    = (u16*)(ws + 4502016);       // 26,214,400 B  [n][6400][64]
  u16* xA    = (u16*)(ws + 30716416);      // 26,214,400 B  [n][6400][64]
  u16* h     = (u16*)(ws + 56930816);      // 54,067,200 B  [n][6600][128]
  u16* wtb   = (u16*)(ws + 110998016);     // 294,912 B     [9][128][128]
  u16* wrb   = (u16*)(ws + 111292928);     // 16,384 B      [128][64]

  kprep<<<dim3(50,32), 256, 0, stream>>>(x, xT);
  kzero<<<50, 256, 0, stream>>>(xm);
  kmean<<<dim3(8,32), 256, 0, stream>>>(xT, xm);
  kp<<<dim3(32,32), 64, 0, stream>>>(xm, w2, b2p, Ab, p, rsA);
  kxa<<<dim3(32,32), 256, 0, stream>>>(xT, Ab, xA);
  kwt<<<576, 256, 0, stream>>>(wt, wtb);
  kwr<<<32, 256, 0, stream>>>(wrw, g2, v2, gr, vr, wrb);
  khpad<<<dim3(32,2), 256, 0, stream>>>(h);
  ks<<<dim3(64,32), 256, 0, stream>>>(xT, w3, p, s);
  ky<<<dim3(50,32), 256, 0, stream>>>(xA, w4, s, b3, b4, g1, bb1, m1, v1, rsA, h);
  ktcn<<<dim3(50,32), 256, 0, stream>>>(h, wtb, wrb, xT, bt, g2, bb2, m2, v2, gr, bbr, mr, vr, brb, out);
}

// Round 4
// 501.058 us; speedup vs baseline: 1.3570x; 1.3570x over previous
//
#include <hip/hip_runtime.h>
#include <hip/hip_bf16.h>

typedef unsigned short u16;
typedef unsigned int u32;
typedef unsigned long long u64;
typedef __attribute__((ext_vector_type(8))) short short8;
typedef __attribute__((ext_vector_type(4))) float f32x4;

#define DI __device__ __forceinline__

DI float b2f(u16 v){ u32 u = ((u32)v) << 16; float f; __builtin_memcpy(&f, &u, 4); return f; }
DI u16 f2bu(float f){ __hip_bfloat16 h = __float2bfloat16(f); u16 u; __builtin_memcpy(&u, &h, 2); return u; }

// ---------- kprep: xT[n][x=(t,v)][ci] = bf16(x[n][ci][x])  (fp32 -> bf16 transpose) ----------
__global__ __launch_bounds__(256) void kprep(const float* __restrict__ x, u16* __restrict__ xT){
  __shared__ u16 tile[128*72];
  const int xb = blockIdx.x, n = blockIdx.y, tid = threadIdx.x;
  const int x0 = xb*128;
  const int ci = tid>>2, part = tid&3;
  const float* src = x + ((size_t)(n*64+ci))*6400 + x0 + part*32;
  #pragma unroll
  for (int i=0;i<8;i++){
    float4 f = ((const float4*)src)[i];
    const int col = part*32 + i*4;
    tile[(col+0)*72+ci] = f2bu(f.x);
    tile[(col+1)*72+ci] = f2bu(f.y);
    tile[(col+2)*72+ci] = f2bu(f.z);
    tile[(col+3)*72+ci] = f2bu(f.w);
  }
  __syncthreads();
  const int row = tid>>1, half = tid&1;
  short8* dst = (short8*)(xT + ((size_t)n*6400 + x0 + row)*64 + half*32);
  const short8* s8 = (const short8*)(tile + row*72 + half*32);
  #pragma unroll
  for (int i=0;i<4;i++) dst[i] = s8[i];
}

// ---------- kzero: xm = 0 ----------
__global__ __launch_bounds__(256) void kzero(float* __restrict__ xm){
  const int i = blockIdx.x*1024 + threadIdx.x*4;   // 50 blocks -> 51200 floats
  float4 z = {0.f,0.f,0.f,0.f};
  *(float4*)(xm + i) = z;
}

// ---------- kmean: xm[n][c][v] += partial mean_t xT ----------
__global__ __launch_bounds__(256) void kmean(const u16* __restrict__ xT, float* __restrict__ xm){
  __shared__ float part[4][1600];
  const int seg = blockIdx.x, n = blockIdx.y, tid = threadIdx.x;
  const int tg = tid>>6, c = tid&63;
  float acc[25];
  #pragma unroll
  for (int v=0;v<25;v++) acc[v]=0.f;
  for (int t = seg*32 + tg; t < seg*32 + 32; t += 4){
    const u16* base = xT + ((size_t)n*6400 + t*25)*64 + c;
    #pragma unroll
    for (int v=0;v<25;v++) acc[v] += b2f(base[v*64]);
  }
  #pragma unroll
  for (int v=0;v<25;v++) part[tg][v*64+c] = acc[v];
  __syncthreads();
  for (int idx = tid; idx < 1600; idx += 256){
    const int v = idx>>6, cc = idx&63;
    const float m = part[0][idx]+part[1][idx]+part[2][idx]+part[3][idx];
    atomicAdd(&xm[(n*64+cc)*25+v], m*(1.f/256.f));
  }
}

// ---------- kp: p[n][c][v] = softmax_v(-(w2@xm+b2));  rsA[u]=sum_v A[u,v] ----------
__global__ __launch_bounds__(64) void kp(const float* __restrict__ xm, const float* __restrict__ w2,
                                         const float* __restrict__ b2p, const float* __restrict__ Ab,
                                         float* __restrict__ p, float* __restrict__ rsA){
  const int c = blockIdx.x, n = blockIdx.y, lane = threadIdx.x;
  __shared__ float sc[32];
  __shared__ float red[2];
  float neg = 0.f;
  if (lane < 25){
    float acc = b2p[c];
    for (int k = 0; k < 64; k++) acc += w2[c*64 + k] * xm[(n*64 + k)*25 + lane];
    neg = -acc;
    sc[lane] = neg;
  }
  __syncthreads();
  if (lane == 0){
    float m = sc[0];
    for (int i = 1; i < 25; i++) m = fmaxf(m, sc[i]);
    red[0] = m;
  }
  __syncthreads();
  float e = 0.f;
  if (lane < 25){ e = expf(neg - red[0]); sc[lane] = e; }
  __syncthreads();
  if (lane == 0){
    float ssum = 0.f;
    for (int i = 0; i < 25; i++) ssum += sc[i];
    red[1] = ssum;
  }
  __syncthreads();
  if (lane < 25) p[(n*32 + c)*25 + lane] = e / red[1];
  if (n == 0 && c == 0 && lane < 25){
    float r = 0.f;
    for (int v = 0; v < 25; v++) r += Ab[lane*25 + v];
    rsA[lane] = r;
  }
}

// ---------- kxa: xA[n][x=(t,u)][k] = bf16( sum_v A[u,v] * xT[n][(t,v)][k] ) ----------
__global__ __launch_bounds__(256) void kxa(const u16* __restrict__ xT, const float* __restrict__ Ab,
                                           u16* __restrict__ xA){
  __shared__ float xl[200*68];
  __shared__ float al[625];
  const int tc = blockIdx.x, n = blockIdx.y, tid = threadIdx.x;
  const int x0t = tc * 200;
  for (int i = tid; i < 625; i += 256) al[i] = Ab[i];
  for (int idx = tid; idx < 1600; idx += 256){
    const int r = idx>>3, i = idx&7;
    short8 v = *(const short8*)(xT + ((size_t)n*6400 + x0t + r)*64 + i*8);
    float* dst = xl + r*68 + i*8;
    #pragma unroll
    for (int e=0;e<8;e++) dst[e] = b2f((u16)v[e]);
  }
  __syncthreads();
  if (tid < 200){
    const int t_ = tid / 25, u = tid % 25;
    float acc[64];
    #pragma unroll
    for (int k = 0; k < 64; k++) acc[k] = 0.f;
    const float* arow = al + u*25;
    for (int v = 0; v < 25; v++){
      const float a = arow[v];
      const float* xr = xl + (t_*25 + v)*68;
      #pragma unroll
      for (int k = 0; k < 64; k++) acc[k] += a * xr[k];
    }
    u16* dst = xA + ((size_t)n*6400 + x0t + tid)*64;
    #pragma unroll
    for (int k = 0; k < 64; k += 4){
      u64 pk = (u64)f2bu(acc[k]) | ((u64)f2bu(acc[k+1])<<16)
             | ((u64)f2bu(acc[k+2])<<32) | ((u64)f2bu(acc[k+3])<<48);
      *(u64*)(dst + k) = pk;
    }
  }
}

// ---------- kwt: wtb[dt][co][ci] = bf16(wt[co][ci][dt]) ----------
__global__ __launch_bounds__(256) void kwt(const float* __restrict__ wt, u16* __restrict__ wtb){
  const int o = blockIdx.x*256 + threadIdx.x;   // < 147456
  const int dt = o >> 14, rem = o & 16383;
  wtb[o] = f2bu(wt[rem*9 + dt]);
}

// ---------- kwr: wrb[co][ci] = bf16( wr[co][ci] * R0[co] / E0[co] ) ----------
__global__ __launch_bounds__(256) void kwr(const float* __restrict__ wrw, const float* __restrict__ g2,
                                           const float* __restrict__ v2, const float* __restrict__ gr,
                                           const float* __restrict__ vr, u16* __restrict__ wrb){
  const int o = blockIdx.x*256 + threadIdx.x;   // < 8192
  const int co = o >> 6;
  const float E0 = g2[co]*rsqrtf(v2[co]+1e-5f);
  const float R0 = gr[co]*rsqrtf(vr[co]+1e-5f);
  wrb[o] = f2bu(wrw[o]*R0/E0);
}

// ---------- khpad: zero t-pad rows of h ----------
__global__ __launch_bounds__(256) void khpad(u16* __restrict__ h){
  const int n = blockIdx.x, side = blockIdx.y, tid = threadIdx.x;
  short8* base = (short8*)(h + ((size_t)n*6600 + (side ? 6500 : 0))*128);
  short8 z = {0,0,0,0,0,0,0,0};
  for (int i = tid; i < 1600; i += 256) base[i] = z;
}

// ---------- ks: s[n][co][t] = sum_v p[n][co&31][v] * (w3@x)[n][co][(t,v)] ----------
// Atomic-free: GEMM -> z3 to LDS (unique writer per element) -> deterministic 25-term reduce.
__global__ __launch_bounds__(256) void ks(const u16* __restrict__ xT, const float* __restrict__ w3,
                                          const float* __restrict__ p, float* __restrict__ s){
  __shared__ __align__(16) char smem[53248];   // phase1: aL(18432) + bL(18432); phase2: z3 fp32 [128][104]
  __shared__ float pL[800];
  __shared__ float sL[512];
  u16* aL = (u16*)smem;
  u16* bL = (u16*)(smem + 18432);
  float* z3 = (float*)smem;
  const int xb = blockIdx.x, n = blockIdx.y, tid = threadIdx.x;
  const int x0 = xb*100, t0 = xb*4;
  const int row = tid >> 1, half = tid & 1;
  { // A: bf16(w3[128][64])
    const float* src = w3 + row*64 + half*32;
    u16* dst = aL + row*72 + half*32;
    #pragma unroll
    for (int i=0;i<8;i++){
      float4 f = ((const float4*)src)[i];
      dst[i*4+0]=f2bu(f.x); dst[i*4+1]=f2bu(f.y); dst[i*4+2]=f2bu(f.z); dst[i*4+3]=f2bu(f.w);
    }
  }
  { // B: xT rows x0..x0+99, rows 100..127 zero
    short8* dst = (short8*)(bL + row*72 + half*32);
    if (row < 100){
      const short8* src = (const short8*)(xT + ((size_t)n*6400 + x0 + row)*64 + half*32);
      #pragma unroll
      for (int i=0;i<4;i++) dst[i] = src[i];
    } else {
      short8 z = {0,0,0,0,0,0,0,0};
      #pragma unroll
      for (int i=0;i<4;i++) dst[i] = z;
    }
  }
  for (int i = tid; i < 800; i += 256) pL[i] = p[n*800 + i];
  __syncthreads();
  const int wave = tid>>6, lane = tid&63, q = lane>>4, l = lane&15;
  const int wr = wave>>1, wc = wave&1;
  f32x4 acc[4][4];
  #pragma unroll
  for (int i=0;i<4;i++)
    #pragma unroll
    for (int j=0;j<4;j++){ f32x4 z0 = {0.f,0.f,0.f,0.f}; acc[i][j] = z0; }
  #pragma unroll
  for (int ksi = 0; ksi < 2; ksi++){
    const int kb = ksi*32 + q*8;
    short8 af[4], bf[4];
    #pragma unroll
    for (int i=0;i<4;i++) af[i] = *(const short8*)(aL + (wr*64 + i*16 + l)*72 + kb);
    #pragma unroll
    for (int j=0;j<4;j++) bf[j] = *(const short8*)(bL + (wc*64 + j*16 + l)*72 + kb);
    #pragma unroll
    for (int i=0;i<4;i++)
      #pragma unroll
      for (int j=0;j<4;j++)
        acc[i][j] = __builtin_amdgcn_mfma_f32_16x16x32_bf16(af[i], bf[j], acc[i][j], 0, 0, 0);
  }
  __syncthreads();   // fragments consumed; smem now becomes z3
  #pragma unroll
  for (int i=0;i<4;i++){
    const int co0 = wr*64 + i*16 + q*4;
    #pragma unroll
    for (int j=0;j<4;j++){
      const int colx = wc*64 + j*16 + l;
      if (colx < 100){
        #pragma unroll
        for (int r=0;r<4;r++) z3[(co0 + r)*104 + colx] = acc[i][j][r];
      }
    }
  }
  __syncthreads();
  for (int idx = tid; idx < 512; idx += 256){
    const int co = idx >> 2, tt = idx & 3;
    const float* zr = z3 + co*104 + tt*25;
    const float* pr = pL + (co & 31)*25;
    float acc2 = 0.f;
    #pragma unroll
    for (int v=0; v<25; v++) acc2 += zr[v]*pr[v];
    s[((size_t)n*128 + co)*256 + t0 + tt] = acc2;
  }
}

// ---------- ky: h[n][x+100][co] = bf16(relu(bn1(w4@xA + b4*rsA[u] + s + b3))) ----------
__global__ __launch_bounds__(256) void ky(const u16* __restrict__ xA, const float* __restrict__ w4,
      const float* __restrict__ s, const float* __restrict__ b3, const float* __restrict__ b4,
      const float* __restrict__ g1, const float* __restrict__ bb1, const float* __restrict__ m1,
      const float* __restrict__ v1, const float* __restrict__ rsA, u16* __restrict__ h){
  __shared__ __align__(16) u16 aL[128*72];
  __shared__ __align__(16) u16 bL[128*72];
  __shared__ float A0[128], A1[128], A2[128];
  __shared__ float sF[1024];
  __shared__ float rs[32];
  const int xb = blockIdx.x, n = blockIdx.y, tid = threadIdx.x;
  const int x0 = xb*128, tlo = x0/25;
  const int row = tid >> 1, half = tid & 1;
  { // A: bf16(w4)
    const float* src = w4 + row*64 + half*32;
    u16* dst = aL + row*72 + half*32;
    #pragma unroll
    for (int i=0;i<8;i++){
      float4 f = ((const float4*)src)[i];
      dst[i*4+0]=f2bu(f.x); dst[i*4+1]=f2bu(f.y); dst[i*4+2]=f2bu(f.z); dst[i*4+3]=f2bu(f.w);
    }
  }
  { // B: xA rows
    const short8* src = (const short8*)(xA + ((size_t)n*6400 + x0 + row)*64 + half*32);
    short8* dst = (short8*)(bL + row*72 + half*32);
    #pragma unroll
    for (int i=0;i<4;i++) dst[i] = src[i];
  }
  if (tid < 128){
    const float scv = g1[tid] * rsqrtf(v1[tid] + 1e-5f);
    A0[tid] = scv;
    A1[tid] = scv * b4[tid];
    A2[tid] = bb1[tid] - m1[tid] * scv;
  }
  if (tid < 32) rs[tid] = (tid < 25) ? rsA[tid] : 0.f;
  __syncthreads();
  for (int idx = tid; idx < 1024; idx += 256){
    const int co = idx >> 3, tt = idx & 7;
    const int t = tlo + tt;
    const float sv = (t < 256) ? s[((size_t)n*128 + co)*256 + t] : 0.f;
    sF[idx] = A0[co] * (sv + b3[co]) + A2[co];
  }
  const int wave = tid>>6, lane = tid&63, q = lane>>4, l = lane&15;
  const int wr = wave>>1, wc = wave&1;
  f32x4 acc[4][4];
  #pragma unroll
  for (int i=0;i<4;i++)
    #pragma unroll
    for (int j=0;j<4;j++){ f32x4 z0 = {0.f,0.f,0.f,0.f}; acc[i][j] = z0; }
  #pragma unroll
  for (int ksi = 0; ksi < 2; ksi++){
    const int kb = ksi*32 + q*8;
    short8 af[4], bf[4];
    #pragma unroll
    for (int i=0;i<4;i++) af[i] = *(const short8*)(aL + (wr*64 + i*16 + l)*72 + kb);
    #pragma unroll
    for (int j=0;j<4;j++) bf[j] = *(const short8*)(bL + (wc*64 + j*16 + l)*72 + kb);
    #pragma unroll
    for (int i=0;i<4;i++)
      #pragma unroll
      for (int j=0;j<4;j++)
        acc[i][j] = __builtin_amdgcn_mfma_f32_16x16x32_bf16(af[i], bf[j], acc[i][j], 0, 0, 0);
  }
  __syncthreads();
  #pragma unroll
  for (int i=0;i<4;i++){
    const int co0 = wr*64 + i*16 + q*4;
    #pragma unroll
    for (int j=0;j<4;j++){
      const int colx = wc*64 + j*16 + l;
      const int xg = x0 + colx;
      const int u = xg % 25, tt = xg/25 - tlo;
      const float rsu = rs[u];
      u64 pk = 0;
      #pragma unroll
      for (int r=0;r<4;r++){
        const int co = co0 + r;
        float y = A0[co]*acc[i][j][r] + A1[co]*rsu + sF[co*8 + tt];
        y = fmaxf(y, 0.f);
        pk |= ((u64)f2bu(y)) << (16*r);
      }
      *(u64*)(h + ((size_t)n*6600 + xg + 100)*128 + co0) = pk;
    }
  }
}

// ---------- ktcn: out = relu(E0*(conv9(h) + (R0/E0)*wr@x) + E1'), fp32 out [n][co][x] ----------
__global__ __launch_bounds__(256) void ktcn(const u16* __restrict__ h, const u16* __restrict__ wtb,
      const u16* __restrict__ wrb, const u16* __restrict__ xT,
      const float* __restrict__ bt, const float* __restrict__ g2, const float* __restrict__ bb2,
      const float* __restrict__ m2, const float* __restrict__ v2,
      const float* __restrict__ gr, const float* __restrict__ bbr, const float* __restrict__ mr,
      const float* __restrict__ vr, const float* __restrict__ brb,
      float* __restrict__ out){
  __shared__ __align__(16) char smem[69632];
  u16* aL = (u16*)smem;            // 128*136
  u16* bL = (u16*)(smem + 34816);  // 128*136
  float* tr = (float*)smem;        // 128*132 fp32 (reused after GEMM)
  __shared__ float E0s[128], E1s[128];
  const int xb = blockIdx.x, n = blockIdx.y, tid = threadIdx.x;
  const int x0 = xb*128;
  const int wave = tid>>6, lane = tid&63, q = lane>>4, l = lane&15;
  const int wr2 = wave>>1, wc = wave&1;
  const int row = tid >> 1, half = tid & 1;
  if (tid < 128){
    const float scv2 = g2[tid]*rsqrtf(v2[tid]+1e-5f);
    const float scvr = gr[tid]*rsqrtf(vr[tid]+1e-5f);
    E0s[tid] = scv2;
    E1s[tid] = scv2*bt[tid] + bb2[tid] - m2[tid]*scv2
             + (bbr[tid] - mr[tid]*scvr + scvr*brb[tid]);
  }
  f32x4 acc[4][4];
  #pragma unroll
  for (int i=0;i<4;i++)
    #pragma unroll
    for (int j=0;j<4;j++){ f32x4 z0 = {0.f,0.f,0.f,0.f}; acc[i][j] = z0; }
  #pragma unroll 1
  for (int dt = 0; dt < 9; dt++){
    __syncthreads();
    {
      const short8* src = (const short8*)(wtb + dt*16384 + row*128 + half*64);
      short8* dst = (short8*)(aL + row*136 + half*64);
      #pragma unroll
      for (int i = 0; i < 8; i++) dst[i] = src[i];
    }
    {
      const short8* src = (const short8*)(h + ((size_t)n*6600 + x0 + dt*25 + row)*128 + half*64);
      short8* dst = (short8*)(bL + row*136 + half*64);
      #pragma unroll
      for (int i = 0; i < 8; i++) dst[i] = src[i];
    }
    __syncthreads();
    #pragma unroll
    for (int ksi = 0; ksi < 4; ksi++){
      const int kb = ksi*32 + q*8;
      short8 af[4], bf[4];
      #pragma unroll
      for (int i=0;i<4;i++) af[i] = *(const short8*)(aL + (wr2*64 + i*16 + l)*136 + kb);
      #pragma unroll
      for (int j=0;j<4;j++) bf[j] = *(const short8*)(bL + (wc*64 + j*16 + l)*136 + kb);
      #pragma unroll
      for (int i=0;i<4;i++)
        #pragma unroll
        for (int j=0;j<4;j++)
          acc[i][j] = __builtin_amdgcn_mfma_f32_16x16x32_bf16(af[i], bf[j], acc[i][j], 0, 0, 0);
    }
  }
  // residual tap: A = wrb (pre-scaled), B = xT rows, K = 64
  __syncthreads();
  {
    const short8* srcA = (const short8*)(wrb + row*64 + half*32);
    short8* dstA = (short8*)(aL + row*136 + half*32);
    #pragma unroll
    for (int i = 0; i < 4; i++) dstA[i] = srcA[i];
    const short8* srcB = (const short8*)(xT + ((size_t)n*6400 + x0 + row)*64 + half*32);
    short8* dstB = (short8*)(bL + row*136 + half*32);
    #pragma unroll
    for (int i = 0; i < 4; i++) dstB[i] = srcB[i];
  }
  __syncthreads();
  #pragma unroll
  for (int ksi = 0; ksi < 2; ksi++){
    const int kb = ksi*32 + q*8;
    short8 af[4], bf[4];
    #pragma unroll
    for (int i=0;i<4;i++) af[i] = *(const short8*)(aL + (wr2*64 + i*16 + l)*136 + kb);
    #pragma unroll
    for (int j=0;j<4;j++) bf[j] = *(const short8*)(bL + (wc*64 + j*16 + l)*136 + kb);
    #pragma unroll
    for (int i=0;i<4;i++)
      #pragma unroll
      for (int j=0;j<4;j++)
        acc[i][j] = __builtin_amdgcn_mfma_f32_16x16x32_bf16(af[i], bf[j], acc[i][j], 0, 0, 0);
  }
  __syncthreads();
  #pragma unroll
  for (int i=0;i<4;i++){
    const int co0 = wr2*64 + i*16 + q*4;
    #pragma unroll
    for (int j=0;j<4;j++){
      const int colx = wc*64 + j*16 + l;
      #pragma unroll
      for (int r=0;r<4;r++){
        const float yv = E0s[co0+r]*acc[i][j][r] + E1s[co0+r];
        tr[(co0+r)*132 + colx] = fmaxf(yv, 0.f);
      }
    }
  }
  __syncthreads();
  {
    const float4* s4 = (const float4*)(tr + row*132 + half*64);
    float4* d4 = (float4*)(out + ((size_t)n*128 + row)*6400 + x0 + half*64);
    #pragma unroll
    for (int i = 0; i < 16; i++) d4[i] = s4[i];
  }
}

extern "C" void kernel_launch(void* const* d_in, const int* in_sizes, int n_in,
                              void* d_out, int out_size, void* d_ws, size_t ws_size,
                              hipStream_t stream){
  const float* x   = (const float*)d_in[0];
  const float* Ab  = (const float*)d_in[1];
  // d_in[2],d_in[3] = w1,b1: dead (softmax cancellation)
  const float* w2  = (const float*)d_in[4];
  const float* b2p = (const float*)d_in[5];
  const float* w3  = (const float*)d_in[6];
  const float* b3  = (const float*)d_in[7];
  const float* w4  = (const float*)d_in[8];
  const float* b4  = (const float*)d_in[9];
  const float* g1  = (const float*)d_in[10];
  const float* bb1 = (const float*)d_in[11];
  const float* m1  = (const float*)d_in[12];
  const float* v1  = (const float*)d_in[13];
  const float* wt  = (const float*)d_in[14];
  const float* bt  = (const float*)d_in[15];
  const float* g2  = (const float*)d_in[16];
  const float* bb2 = (const float*)d_in[17];
  const float* m2  = (const float*)d_in[18];
  const float* v2  = (const float*)d_in[19];
  const float* wrw = (const float*)d_in[20];
  const float* brb = (const float*)d_in[21];
  const float* gr  = (const float*)d_in[22];
  const float* bbr = (const float*)d_in[23];
  const float* mr  = (const float*)d_in[24];
  const float* vr  = (const float*)d_in[25];
  float* out = (float*)d_out;

  char* ws = (char*)d_ws;
  float* xm  = (float*)(ws);               // 204,800 B
  float* p   = (float*)(ws + 204800);      // 102,400 B
  float* rsA = (float*)(ws + 307200);      // 512 B
  float* s   = (float*)(ws + 307712);      // 4,194,304 B
  u16* xT    = (u16*)(ws + 4502016);       // 26,214,400 B  [n][6400][64]
  u16* xA    = (u16*)(ws + 30716416);      // 26,214,400 B  [n][6400][64]
  u16* h     = (u16*)(ws + 56930816);      // 54,067,200 B  [n][6600][128]
  u16* wtb   = (u16*)(ws + 110998016);     // 294,912 B     [9][128][128]
  u16* wrb   = (u16*)(ws + 111292928);     // 16,384 B      [128][64]

  kprep<<<dim3(50,32), 256, 0, stream>>>(x, xT);
  kzero<<<50, 256, 0, stream>>>(xm);
  kmean<<<dim3(8,32), 256, 0, stream>>>(xT, xm);
  kp<<<dim3(32,32), 64, 0, stream>>>(xm, w2, b2p, Ab, p, rsA);
  kxa<<<dim3(32,32), 256, 0, stream>>>(xT, Ab, xA);
  kwt<<<576, 256, 0, stream>>>(wt, wtb);
  kwr<<<32, 256, 0, stream>>>(wrw, g2, v2, gr, vr, wrb);
  khpad<<<dim3(32,2), 256, 0, stream>>>(h);
  ks<<<dim3(64,32), 256, 0, stream>>>(xT, w3, p, s);
  ky<<<dim3(50,32), 256, 0, stream>>>(xA, w4, s, b3, b4, g1, bb1, m1, v1, rsA, h);
  ktcn<<<dim3(50,32), 256, 0, stream>>>(h, wtb, wrb, xT, bt, g2, bb2, m2, v2, gr, bbr, mr, vr, brb, out);
}

// Round 5
// 493.414 us; speedup vs baseline: 1.3781x; 1.0155x over previous
//
#include <hip/hip_runtime.h>
#include <hip/hip_bf16.h>

typedef unsigned short u16;
typedef unsigned int u32;
typedef unsigned long long u64;
typedef __attribute__((ext_vector_type(8))) short short8;
typedef __attribute__((ext_vector_type(4))) float f32x4;

#define DI __device__ __forceinline__

DI float b2f(u16 v){ u32 u = ((u32)v) << 16; float f; __builtin_memcpy(&f, &u, 4); return f; }
DI u16 f2bu(float f){ __hip_bfloat16 h = __float2bfloat16(f); u16 u; __builtin_memcpy(&u, &h, 2); return u; }

// async 16B global->LDS DMA; LDS dest = wave-uniform base + lane*16
DI void gll16(const u16* g, u16* l){
  __builtin_amdgcn_global_load_lds((const __attribute__((address_space(1))) void*)g,
                                   (__attribute__((address_space(3))) void*)l, 16, 0, 0);
}

// ---------- kprep: xT[n][x=(t,v)][ci] = bf16(x[n][ci][x])  (fp32 -> bf16 transpose) ----------
__global__ __launch_bounds__(256) void kprep(const float* __restrict__ x, u16* __restrict__ xT){
  __shared__ u16 tile[128*72];
  const int xb = blockIdx.x, n = blockIdx.y, tid = threadIdx.x;
  const int x0 = xb*128;
  const int ci = tid>>2, part = tid&3;
  const float* src = x + ((size_t)(n*64+ci))*6400 + x0 + part*32;
  #pragma unroll
  for (int i=0;i<8;i++){
    float4 f = ((const float4*)src)[i];
    const int col = part*32 + i*4;
    tile[(col+0)*72+ci] = f2bu(f.x);
    tile[(col+1)*72+ci] = f2bu(f.y);
    tile[(col+2)*72+ci] = f2bu(f.z);
    tile[(col+3)*72+ci] = f2bu(f.w);
  }
  __syncthreads();
  const int row = tid>>1, half = tid&1;
  short8* dst = (short8*)(xT + ((size_t)n*6400 + x0 + row)*64 + half*32);
  const short8* s8 = (const short8*)(tile + row*72 + half*32);
  #pragma unroll
  for (int i=0;i<4;i++) dst[i] = s8[i];
}

// ---------- kzero: xm = 0 ----------
__global__ __launch_bounds__(256) void kzero(float* __restrict__ xm){
  const int i = blockIdx.x*1024 + threadIdx.x*4;
  float4 z = {0.f,0.f,0.f,0.f};
  *(float4*)(xm + i) = z;
}

// ---------- kmean ----------
__global__ __launch_bounds__(256) void kmean(const u16* __restrict__ xT, float* __restrict__ xm){
  __shared__ float part[4][1600];
  const int seg = blockIdx.x, n = blockIdx.y, tid = threadIdx.x;
  const int tg = tid>>6, c = tid&63;
  float acc[25];
  #pragma unroll
  for (int v=0;v<25;v++) acc[v]=0.f;
  for (int t = seg*32 + tg; t < seg*32 + 32; t += 4){
    const u16* base = xT + ((size_t)n*6400 + t*25)*64 + c;
    #pragma unroll
    for (int v=0;v<25;v++) acc[v] += b2f(base[v*64]);
  }
  #pragma unroll
  for (int v=0;v<25;v++) part[tg][v*64+c] = acc[v];
  __syncthreads();
  for (int idx = tid; idx < 1600; idx += 256){
    const int v = idx>>6, cc = idx&63;
    const float m = part[0][idx]+part[1][idx]+part[2][idx]+part[3][idx];
    atomicAdd(&xm[(n*64+cc)*25+v], m*(1.f/256.f));
  }
}

// ---------- kp ----------
__global__ __launch_bounds__(64) void kp(const float* __restrict__ xm, const float* __restrict__ w2,
                                         const float* __restrict__ b2p, const float* __restrict__ Ab,
                                         float* __restrict__ p, float* __restrict__ rsA){
  const int c = blockIdx.x, n = blockIdx.y, lane = threadIdx.x;
  __shared__ float sc[32];
  __shared__ float red[2];
  float neg = 0.f;
  if (lane < 25){
    float acc = b2p[c];
    for (int k = 0; k < 64; k++) acc += w2[c*64 + k] * xm[(n*64 + k)*25 + lane];
    neg = -acc;
    sc[lane] = neg;
  }
  __syncthreads();
  if (lane == 0){
    float m = sc[0];
    for (int i = 1; i < 25; i++) m = fmaxf(m, sc[i]);
    red[0] = m;
  }
  __syncthreads();
  float e = 0.f;
  if (lane < 25){ e = expf(neg - red[0]); sc[lane] = e; }
  __syncthreads();
  if (lane == 0){
    float ssum = 0.f;
    for (int i = 0; i < 25; i++) ssum += sc[i];
    red[1] = ssum;
  }
  __syncthreads();
  if (lane < 25) p[(n*32 + c)*25 + lane] = e / red[1];
  if (n == 0 && c == 0 && lane < 25){
    float r = 0.f;
    for (int v = 0; v < 25; v++) r += Ab[lane*25 + v];
    rsA[lane] = r;
  }
}

// ---------- kxa ----------
__global__ __launch_bounds__(256) void kxa(const u16* __restrict__ xT, const float* __restrict__ Ab,
                                           u16* __restrict__ xA){
  __shared__ float xl[200*68];
  __shared__ float al[625];
  const int tc = blockIdx.x, n = blockIdx.y, tid = threadIdx.x;
  const int x0t = tc * 200;
  for (int i = tid; i < 625; i += 256) al[i] = Ab[i];
  for (int idx = tid; idx < 1600; idx += 256){
    const int r = idx>>3, i = idx&7;
    short8 v = *(const short8*)(xT + ((size_t)n*6400 + x0t + r)*64 + i*8);
    float* dst = xl + r*68 + i*8;
    #pragma unroll
    for (int e=0;e<8;e++) dst[e] = b2f((u16)v[e]);
  }
  __syncthreads();
  if (tid < 200){
    const int t_ = tid / 25, u = tid % 25;
    float acc[64];
    #pragma unroll
    for (int k = 0; k < 64; k++) acc[k] = 0.f;
    const float* arow = al + u*25;
    for (int v = 0; v < 25; v++){
      const float a = arow[v];
      const float* xr = xl + (t_*25 + v)*68;
      #pragma unroll
      for (int k = 0; k < 64; k++) acc[k] += a * xr[k];
    }
    u16* dst = xA + ((size_t)n*6400 + x0t + tid)*64;
    #pragma unroll
    for (int k = 0; k < 64; k += 4){
      u64 pk = (u64)f2bu(acc[k]) | ((u64)f2bu(acc[k+1])<<16)
             | ((u64)f2bu(acc[k+2])<<32) | ((u64)f2bu(acc[k+3])<<48);
      *(u64*)(dst + k) = pk;
    }
  }
}

// ---------- kwt: wtb[dt][co][ci] = bf16(wt[co][ci][dt]) ----------
__global__ __launch_bounds__(256) void kwt(const float* __restrict__ wt, u16* __restrict__ wtb){
  const int o = blockIdx.x*256 + threadIdx.x;
  const int dt = o >> 14, rem = o & 16383;
  wtb[o] = f2bu(wt[rem*9 + dt]);
}

// ---------- kwr ----------
__global__ __launch_bounds__(256) void kwr(const float* __restrict__ wrw, const float* __restrict__ g2,
                                           const float* __restrict__ v2, const float* __restrict__ gr,
                                           const float* __restrict__ vr, u16* __restrict__ wrb){
  const int o = blockIdx.x*256 + threadIdx.x;
  const int co = o >> 6;
  const float E0 = g2[co]*rsqrtf(v2[co]+1e-5f);
  const float R0 = gr[co]*rsqrtf(vr[co]+1e-5f);
  wrb[o] = f2bu(wrw[o]*R0/E0);
}

// ---------- khpad ----------
__global__ __launch_bounds__(256) void khpad(u16* __restrict__ h){
  const int n = blockIdx.x, side = blockIdx.y, tid = threadIdx.x;
  short8* base = (short8*)(h + ((size_t)n*6600 + (side ? 6500 : 0))*128);
  short8 z = {0,0,0,0,0,0,0,0};
  for (int i = tid; i < 1600; i += 256) base[i] = z;
}

// ---------- ks (atomic-free) ----------
__global__ __launch_bounds__(256) void ks(const u16* __restrict__ xT, const float* __restrict__ w3,
                                          const float* __restrict__ p, float* __restrict__ s){
  __shared__ __align__(16) char smem[53248];
  __shared__ float pL[800];
  u16* aL = (u16*)smem;
  u16* bL = (u16*)(smem + 18432);
  float* z3 = (float*)smem;
  const int xb = blockIdx.x, n = blockIdx.y, tid = threadIdx.x;
  const int x0 = xb*100, t0 = xb*4;
  const int row = tid >> 1, half = tid & 1;
  {
    const float* src = w3 + row*64 + half*32;
    u16* dst = aL + row*72 + half*32;
    #pragma unroll
    for (int i=0;i<8;i++){
      float4 f = ((const float4*)src)[i];
      dst[i*4+0]=f2bu(f.x); dst[i*4+1]=f2bu(f.y); dst[i*4+2]=f2bu(f.z); dst[i*4+3]=f2bu(f.w);
    }
  }
  {
    short8* dst = (short8*)(bL + row*72 + half*32);
    if (row < 100){
      const short8* src = (const short8*)(xT + ((size_t)n*6400 + x0 + row)*64 + half*32);
      #pragma unroll
      for (int i=0;i<4;i++) dst[i] = src[i];
    } else {
      short8 z = {0,0,0,0,0,0,0,0};
      #pragma unroll
      for (int i=0;i<4;i++) dst[i] = z;
    }
  }
  for (int i = tid; i < 800; i += 256) pL[i] = p[n*800 + i];
  __syncthreads();
  const int wave = tid>>6, lane = tid&63, q = lane>>4, l = lane&15;
  const int wr = wave>>1, wc = wave&1;
  f32x4 acc[4][4];
  #pragma unroll
  for (int i=0;i<4;i++)
    #pragma unroll
    for (int j=0;j<4;j++){ f32x4 z0 = {0.f,0.f,0.f,0.f}; acc[i][j] = z0; }
  #pragma unroll
  for (int ksi = 0; ksi < 2; ksi++){
    const int kb = ksi*32 + q*8;
    short8 af[4], bf[4];
    #pragma unroll
    for (int i=0;i<4;i++) af[i] = *(const short8*)(aL + (wr*64 + i*16 + l)*72 + kb);
    #pragma unroll
    for (int j=0;j<4;j++) bf[j] = *(const short8*)(bL + (wc*64 + j*16 + l)*72 + kb);
    #pragma unroll
    for (int i=0;i<4;i++)
      #pragma unroll
      for (int j=0;j<4;j++)
        acc[i][j] = __builtin_amdgcn_mfma_f32_16x16x32_bf16(af[i], bf[j], acc[i][j], 0, 0, 0);
  }
  __syncthreads();
  #pragma unroll
  for (int i=0;i<4;i++){
    const int co0 = wr*64 + i*16 + q*4;
    #pragma unroll
    for (int j=0;j<4;j++){
      const int colx = wc*64 + j*16 + l;
      if (colx < 100){
        #pragma unroll
        for (int r=0;r<4;r++) z3[(co0 + r)*104 + colx] = acc[i][j][r];
      }
    }
  }
  __syncthreads();
  for (int idx = tid; idx < 512; idx += 256){
    const int co = idx >> 2, tt = idx & 3;
    const float* zr = z3 + co*104 + tt*25;
    const float* pr = pL + (co & 31)*25;
    float acc2 = 0.f;
    #pragma unroll
    for (int v=0; v<25; v++) acc2 += zr[v]*pr[v];
    s[((size_t)n*128 + co)*256 + t0 + tt] = acc2;
  }
}

// ---------- ky ----------
__global__ __launch_bounds__(256) void ky(const u16* __restrict__ xA, const float* __restrict__ w4,
      const float* __restrict__ s, const float* __restrict__ b3, const float* __restrict__ b4,
      const float* __restrict__ g1, const float* __restrict__ bb1, const float* __restrict__ m1,
      const float* __restrict__ v1, const float* __restrict__ rsA, u16* __restrict__ h){
  __shared__ __align__(16) u16 aL[128*72];
  __shared__ __align__(16) u16 bL[128*72];
  __shared__ float A0[128], A1[128], A2[128];
  __shared__ float sF[1024];
  __shared__ float rs[32];
  const int xb = blockIdx.x, n = blockIdx.y, tid = threadIdx.x;
  const int x0 = xb*128, tlo = x0/25;
  const int row = tid >> 1, half = tid & 1;
  {
    const float* src = w4 + row*64 + half*32;
    u16* dst = aL + row*72 + half*32;
    #pragma unroll
    for (int i=0;i<8;i++){
      float4 f = ((const float4*)src)[i];
      dst[i*4+0]=f2bu(f.x); dst[i*4+1]=f2bu(f.y); dst[i*4+2]=f2bu(f.z); dst[i*4+3]=f2bu(f.w);
    }
  }
  {
    const short8* src = (const short8*)(xA + ((size_t)n*6400 + x0 + row)*64 + half*32);
    short8* dst = (short8*)(bL + row*72 + half*32);
    #pragma unroll
    for (int i=0;i<4;i++) dst[i] = src[i];
  }
  if (tid < 128){
    const float scv = g1[tid] * rsqrtf(v1[tid] + 1e-5f);
    A0[tid] = scv;
    A1[tid] = scv * b4[tid];
    A2[tid] = bb1[tid] - m1[tid] * scv;
  }
  if (tid < 32) rs[tid] = (tid < 25) ? rsA[tid] : 0.f;
  __syncthreads();
  for (int idx = tid; idx < 1024; idx += 256){
    const int co = idx >> 3, tt = idx & 7;
    const int t = tlo + tt;
    const float sv = (t < 256) ? s[((size_t)n*128 + co)*256 + t] : 0.f;
    sF[idx] = A0[co] * (sv + b3[co]) + A2[co];
  }
  const int wave = tid>>6, lane = tid&63, q = lane>>4, l = lane&15;
  const int wr = wave>>1, wc = wave&1;
  f32x4 acc[4][4];
  #pragma unroll
  for (int i=0;i<4;i++)
    #pragma unroll
    for (int j=0;j<4;j++){ f32x4 z0 = {0.f,0.f,0.f,0.f}; acc[i][j] = z0; }
  #pragma unroll
  for (int ksi = 0; ksi < 2; ksi++){
    const int kb = ksi*32 + q*8;
    short8 af[4], bf[4];
    #pragma unroll
    for (int i=0;i<4;i++) af[i] = *(const short8*)(aL + (wr*64 + i*16 + l)*72 + kb);
    #pragma unroll
    for (int j=0;j<4;j++) bf[j] = *(const short8*)(bL + (wc*64 + j*16 + l)*72 + kb);
    #pragma unroll
    for (int i=0;i<4;i++)
      #pragma unroll
      for (int j=0;j<4;j++)
        acc[i][j] = __builtin_amdgcn_mfma_f32_16x16x32_bf16(af[i], bf[j], acc[i][j], 0, 0, 0);
  }
  __syncthreads();
  #pragma unroll
  for (int i=0;i<4;i++){
    const int co0 = wr*64 + i*16 + q*4;
    #pragma unroll
    for (int j=0;j<4;j++){
      const int colx = wc*64 + j*16 + l;
      const int xg = x0 + colx;
      const int u = xg % 25, tt = xg/25 - tlo;
      const float rsu = rs[u];
      u64 pk = 0;
      #pragma unroll
      for (int r=0;r<4;r++){
        const int co = co0 + r;
        float y = A0[co]*acc[i][j][r] + A1[co]*rsu + sF[co*8 + tt];
        y = fmaxf(y, 0.f);
        pk |= ((u64)f2bu(y)) << (16*r);
      }
      *(u64*)(h + ((size_t)n*6600 + xg + 100)*128 + co0) = pk;
    }
  }
}

// ---------- ktcn v2: resident h-window + async DMA + A-dbuf + XOR-swizzled LDS ----------
// out = relu(E0*(conv9(h) + (R0/E0)*wr@x) + E1'), fp32 out [n][co][x]
__global__ __launch_bounds__(256) void ktcn(const u16* __restrict__ h, const u16* __restrict__ wtb,
      const u16* __restrict__ wrb, const u16* __restrict__ xT,
      const float* __restrict__ bt, const float* __restrict__ g2, const float* __restrict__ bb2,
      const float* __restrict__ m2, const float* __restrict__ v2,
      const float* __restrict__ gr, const float* __restrict__ bbr, const float* __restrict__ mr,
      const float* __restrict__ vr, const float* __restrict__ brb,
      float* __restrict__ out){
  // LDS: [0,83968) hW 328 rows x 128 u16 (chunk-swizzled); [83968,116736) Abuf0; [116736,149504) Abuf1
  // epilogue tr (128x132 fp32 = 67.6 KB) reuses hW region
  __shared__ __align__(16) char smem[149504];
  u16* hW = (u16*)smem;
  u16* Ab0 = (u16*)(smem + 83968);
  u16* Ab1 = (u16*)(smem + 116736);
  float* tr = (float*)smem;
  __shared__ float E0s[128], E1s[128];
  const int xb = blockIdx.x, n = blockIdx.y, tid = threadIdx.x;
  const int x0 = xb*128;
  const int wave = tid>>6, lane = tid&63, q = lane>>4, l = lane&15;
  const int wr2 = wave>>1, wc = wave&1;
  const u16* hbase = h + ((size_t)n*6600 + x0)*128;
  const u16* xtb = xT + ((size_t)n*6400 + x0)*64;

  // ---- stage hW: 5248 swizzled chunks (chunk (r,c) holds global (r, c^(r&15))) ----
  #pragma unroll
  for (int it = 0; it < 20; ++it){
    const int ci = it*256 + tid;
    const int r = ci >> 4, c = ci & 15;
    gll16(hbase + r*128 + ((c ^ (r & 15))<<3), hW + ((it*256 + wave*64)<<3));
  }
  if (tid < 128){   // tail: chunks 5120..5247 (waves 0,1 fully active)
    const int ci = 5120 + tid;
    const int r = ci >> 4, c = ci & 15;
    gll16(hbase + r*128 + ((c ^ (r & 15))<<3), hW + ((5120 + wave*64)<<3));
  }
  // ---- stage A0 ----
  #pragma unroll
  for (int it = 0; it < 8; ++it){
    const int ci = it*256 + tid;
    const int r = ci >> 4, c = ci & 15;
    gll16(wtb + r*128 + ((c ^ (r & 15))<<3), Ab0 + ((it*256 + wave*64)<<3));
  }
  if (tid < 128){
    const float scv2 = g2[tid]*rsqrtf(v2[tid]+1e-5f);
    const float scvr = gr[tid]*rsqrtf(vr[tid]+1e-5f);
    E0s[tid] = scv2;
    E1s[tid] = scv2*bt[tid] + bb2[tid] - m2[tid]*scv2
             + (bbr[tid] - mr[tid]*scvr + scvr*brb[tid]);
  }
  f32x4 acc[4][4];
  #pragma unroll
  for (int i=0;i<4;i++)
    #pragma unroll
    for (int j=0;j<4;j++){ f32x4 z0 = {0.f,0.f,0.f,0.f}; acc[i][j] = z0; }
  __syncthreads();   // hW + A0 ready

  #pragma unroll 1
  for (int dt = 0; dt <= 9; ++dt){
    // prefetch next tap (in flight during this tap's MFMA; drained at the barrier below)
    if (dt < 8){
      const u16* gA = wtb + (dt+1)*16384;
      u16* dA = (dt & 1) ? Ab0 : Ab1;
      #pragma unroll
      for (int it = 0; it < 8; ++it){
        const int ci = it*256 + tid;
        const int r = ci >> 4, c = ci & 15;
        gll16(gA + r*128 + ((c ^ (r & 15))<<3), dA + ((it*256 + wave*64)<<3));
      }
    } else if (dt == 8){
      // residual operands into Ab1: wrb (16 KB) then xT tile (16 KB), 8 chunks/row swizzle
      #pragma unroll
      for (int it = 0; it < 4; ++it){
        const int ci = it*256 + tid;
        const int r = ci >> 3, c = ci & 7;
        gll16(wrb + r*64 + ((c ^ (r & 7))<<3), Ab1 + ((it*256 + wave*64)<<3));
      }
      #pragma unroll
      for (int it = 0; it < 4; ++it){
        const int ci = it*256 + tid;
        const int r = ci >> 3, c = ci & 7;
        gll16(xtb + r*64 + ((c ^ (r & 7))<<3), Ab1 + 8192 + ((it*256 + wave*64)<<3));
      }
    }
    if (dt < 9){
      const u16* A = (dt & 1) ? Ab1 : Ab0;
      #pragma unroll
      for (int ksi = 0; ksi < 4; ksi++){
        const int c0 = ksi*4 + q;
        short8 af[4], bf[4];
        #pragma unroll
        for (int i=0;i<4;i++){
          const int r = wr2*64 + i*16 + l;
          af[i] = *(const short8*)(A + ((r<<4) + (c0 ^ (r & 15)))*8);
        }
        #pragma unroll
        for (int j=0;j<4;j++){
          const int r = dt*25 + wc*64 + j*16 + l;
          bf[j] = *(const short8*)(hW + (((r<<4) + (c0 ^ (r & 15)))<<3));
        }
        #pragma unroll
        for (int i=0;i<4;i++)
          #pragma unroll
          for (int j=0;j<4;j++)
            acc[i][j] = __builtin_amdgcn_mfma_f32_16x16x32_bf16(af[i], bf[j], acc[i][j], 0, 0, 0);
      }
    } else {
      // residual tap: K=64, A=wrb (pre-scaled), B=xT tile, both in Ab1 with 8-chunk swizzle
      const u16* A = Ab1;
      const u16* B = Ab1 + 8192;
      #pragma unroll
      for (int ksi = 0; ksi < 2; ksi++){
        const int c0 = ksi*4 + q;
        short8 af[4], bf[4];
        #pragma unroll
        for (int i=0;i<4;i++){
          const int r = wr2*64 + i*16 + l;
          af[i] = *(const short8*)(A + (((r<<3) + (c0 ^ (r & 7)))<<3));
        }
        #pragma unroll
        for (int j=0;j<4;j++){
          const int r = wc*64 + j*16 + l;
          bf[j] = *(const short8*)(B + (((r<<3) + (c0 ^ (r & 7)))<<3));
        }
        #pragma unroll
        for (int i=0;i<4;i++)
          #pragma unroll
          for (int j=0;j<4;j++)
            acc[i][j] = __builtin_amdgcn_mfma_f32_16x16x32_bf16(af[i], bf[j], acc[i][j], 0, 0, 0);
      }
    }
    __syncthreads();
  }

  // ---- epilogue: scale+relu into tr (reuses hW region), then coalesced fp32 store ----
  #pragma unroll
  for (int i=0;i<4;i++){
    const int co0 = wr2*64 + i*16 + q*4;
    #pragma unroll
    for (int j=0;j<4;j++){
      const int colx = wc*64 + j*16 + l;
      #pragma unroll
      for (int r=0;r<4;r++){
        const float yv = E0s[co0+r]*acc[i][j][r] + E1s[co0+r];
        tr[(co0+r)*132 + colx] = fmaxf(yv, 0.f);
      }
    }
  }
  __syncthreads();
  {
    const int row = tid >> 1, half = tid & 1;
    const float4* s4 = (const float4*)(tr + row*132 + half*64);
    float4* d4 = (float4*)(out + ((size_t)n*128 + row)*6400 + x0 + half*64);
    #pragma unroll
    for (int i = 0; i < 16; i++) d4[i] = s4[i];
  }
}

extern "C" void kernel_launch(void* const* d_in, const int* in_sizes, int n_in,
                              void* d_out, int out_size, void* d_ws, size_t ws_size,
                              hipStream_t stream){
  const float* x   = (const float*)d_in[0];
  const float* Ab  = (const float*)d_in[1];
  // d_in[2],d_in[3] = w1,b1: dead (softmax cancellation)
  const float* w2  = (const float*)d_in[4];
  const float* b2p = (const float*)d_in[5];
  const float* w3  = (const float*)d_in[6];
  const float* b3  = (const float*)d_in[7];
  const float* w4  = (const float*)d_in[8];
  const float* b4  = (const float*)d_in[9];
  const float* g1  = (const float*)d_in[10];
  const float* bb1 = (const float*)d_in[11];
  const float* m1  = (const float*)d_in[12];
  const float* v1  = (const float*)d_in[13];
  const float* wt  = (const float*)d_in[14];
  const float* bt  = (const float*)d_in[15];
  const float* g2  = (const float*)d_in[16];
  const float* bb2 = (const float*)d_in[17];
  const float* m2  = (const float*)d_in[18];
  const float* v2  = (const float*)d_in[19];
  const float* wrw = (const float*)d_in[20];
  const float* brb = (const float*)d_in[21];
  const float* gr  = (const float*)d_in[22];
  const float* bbr = (const float*)d_in[23];
  const float* mr  = (const float*)d_in[24];
  const float* vr  = (const float*)d_in[25];
  float* out = (float*)d_out;

  char* ws = (char*)d_ws;
  float* xm  = (float*)(ws);               // 204,800 B
  float* p   = (float*)(ws + 204800);      // 102,400 B
  float* rsA = (float*)(ws + 307200);      // 512 B
  float* s   = (float*)(ws + 307712);      // 4,194,304 B
  u16* xT    = (u16*)(ws + 4502016);       // 26,214,400 B  [n][6400][64]
  u16* xA    = (u16*)(ws + 30716416);      // 26,214,400 B  [n][6400][64]
  u16* h     = (u16*)(ws + 56930816);      // 54,067,200 B  [n][6600][128]
  u16* wtb   = (u16*)(ws + 110998016);     // 294,912 B     [9][128][128]
  u16* wrb   = (u16*)(ws + 111292928);     // 16,384 B      [128][64]

  kprep<<<dim3(50,32), 256, 0, stream>>>(x, xT);
  kzero<<<50, 256, 0, stream>>>(xm);
  kmean<<<dim3(8,32), 256, 0, stream>>>(xT, xm);
  kp<<<dim3(32,32), 64, 0, stream>>>(xm, w2, b2p, Ab, p, rsA);
  kxa<<<dim3(32,32), 256, 0, stream>>>(xT, Ab, xA);
  kwt<<<576, 256, 0, stream>>>(wt, wtb);
  kwr<<<32, 256, 0, stream>>>(wrw, g2, v2, gr, vr, wrb);
  khpad<<<dim3(32,2), 256, 0, stream>>>(h);
  ks<<<dim3(64,32), 256, 0, stream>>>(xT, w3, p, s);
  ky<<<dim3(50,32), 256, 0, stream>>>(xA, w4, s, b3, b4, g1, bb1, m1, v1, rsA, h);
  ktcn<<<dim3(50,32), 256, 0, stream>>>(h, wtb, wrb, xT, bt, g2, bb2, m2, v2, gr, bbr, mr, vr, brb, out);
}